// Round 4
// baseline (741.529 us; speedup 1.0000x reference)
//
#include <hip/hip_runtime.h>
#include <hip/hip_bf16.h>
#include <stdint.h>

// Problem constants (b=16, l=4096, d=256, c=256, qk_dim=256, heads=8)
// Inputs: float32. Outputs: FLOAT32 (reference is f32 end-to-end):
//   out[0..65536)      k  [8,256,32]
//   out[65536..131072) v  [8,256,32]
//   out[131072..196608) x_global [256,256]
#define NPTS 65536   // b*l
#define DD   256     // feature dim
#define CC   256     // clusters

// ---------------------------------------------------------------------------
// K1: normalize cluster means (f32), zero sums + bins
__global__ __launch_bounds__(256) void k_prep(const float* __restrict__ xm,
                                              float* __restrict__ means_n,
                                              float* __restrict__ sums,
                                              int* __restrict__ bins) {
    __shared__ float red[256];
    int c = blockIdx.x, t = threadIdx.x;
    float v = xm[c * DD + t];
    red[t] = v * v;
    __syncthreads();
    for (int off = 128; off > 0; off >>= 1) {
        if (t < off) red[t] += red[t + off];
        __syncthreads();
    }
    float inv = 1.0f / fmaxf(sqrtf(red[0]), 1e-12f);
    means_n[c * DD + t] = v * inv;
    sums[c * DD + t] = 0.0f;
    if (c == 0) bins[t] = 0;
}

// ---------------------------------------------------------------------------
// K2: per-point argmax over similarity to 256 means + row inv-norm.
// 64 points/block staged f32 in LDS (64KB); 16 tx (cluster groups) x 16 ty
// (point groups); register tile 4 points x 16 clusters. Argmax is invariant
// to the positive per-row scale, so raw x is used for dists; inv_norm is
// applied only in the scatter. Final argmax reduce via LDS.
__global__ __launch_bounds__(256) void k_assign(const float* __restrict__ x,
                                                const float* __restrict__ means_n,
                                                int* __restrict__ buckets,
                                                float* __restrict__ inv_norm) {
    __shared__ __align__(16) float xs[64 * 256];   // 64KB, [point][coord]
    int t = threadIdx.x;
    int tx = t & 15, ty = t >> 4;
    int n0 = blockIdx.x * 64;

    // stage: 64 rows x 256 f32 -> LDS, float4 per load, fully coalesced
    const float4* src = (const float4*)(x + (size_t)n0 * DD);
    float4* dst = (float4*)xs;
    for (int i = 0; i < 16; i++) dst[t + 256 * i] = src[t + 256 * i];
    __syncthreads();

    float acc[4][16];
#pragma unroll
    for (int pp = 0; pp < 4; pp++)
#pragma unroll
        for (int cc = 0; cc < 16; cc++) acc[pp][cc] = 0.0f;
    float ss[4] = {0.f, 0.f, 0.f, 0.f};

    const float* mbase = means_n + (size_t)(tx * 16) * DD;
    for (int j4 = 0; j4 < 64; j4++) {
        float4 xv[4];
#pragma unroll
        for (int pp = 0; pp < 4; pp++) {
            xv[pp] = *(const float4*)(xs + (ty * 4 + pp) * 256 + j4 * 4);
            ss[pp] += xv[pp].x * xv[pp].x + xv[pp].y * xv[pp].y +
                      xv[pp].z * xv[pp].z + xv[pp].w * xv[pp].w;
        }
#pragma unroll
        for (int cc = 0; cc < 16; cc++) {
            float4 m = *(const float4*)(mbase + cc * DD + j4 * 4);
#pragma unroll
            for (int pp = 0; pp < 4; pp++) {
                acc[pp][cc] += xv[pp].x * m.x + xv[pp].y * m.y +
                               xv[pp].z * m.z + xv[pp].w * m.w;
            }
        }
    }

    // inv_norm (each tx lane computed the full row sum redundantly)
    if (tx == 0) {
#pragma unroll
        for (int pp = 0; pp < 4; pp++) {
            inv_norm[n0 + ty * 4 + pp] = 1.0f / fmaxf(sqrtf(ss[pp]), 1e-12f);
        }
    }

    // per-thread argmax over its 16 (ascending) clusters; strict > keeps first
    float bv[4]; int bi[4];
#pragma unroll
    for (int pp = 0; pp < 4; pp++) {
        bv[pp] = acc[pp][0]; bi[pp] = tx * 16;
#pragma unroll
        for (int cc = 1; cc < 16; cc++) {
            if (acc[pp][cc] > bv[pp]) { bv[pp] = acc[pp][cc]; bi[pp] = tx * 16 + cc; }
        }
    }

    // LDS-based final reduce (reuse xs after all reads complete)
    __syncthreads();
    float* bvs = xs;                   // [64 points][16 tx-groups]
    int*   bis = (int*)(xs + 64 * 16); // [64 points][16 tx-groups]
#pragma unroll
    for (int pp = 0; pp < 4; pp++) {
        int p = ty * 4 + pp;
        bvs[p * 16 + tx] = bv[pp];
        bis[p * 16 + tx] = bi[pp];
    }
    __syncthreads();
    if (t < 64) {
        float best = bvs[t * 16];
        int besti  = bis[t * 16];
        for (int i = 1; i < 16; i++) {
            float v2 = bvs[t * 16 + i];
            int   i2 = bis[t * 16 + i];
            // ascending i => ascending cluster ranges; strict > keeps lowest
            if (v2 > best || (v2 == best && i2 < besti)) { best = v2; besti = i2; }
        }
        buckets[n0 + t] = besti;
    }
}

// ---------------------------------------------------------------------------
// K3b: bin counts (histogram of buckets). grid 32 blocks x 256 thr.
__global__ __launch_bounds__(256) void k_bins(const int* __restrict__ buckets,
                                              int* __restrict__ bins) {
    __shared__ int hist[256];
    int t = threadIdx.x;
    hist[t] = 0;
    __syncthreads();
    int n0 = blockIdx.x * 2048;
    for (int i = 0; i < 8; i++)
        atomicAdd(&hist[buckets[n0 + i * 256 + t] & 255], 1);
    __syncthreads();
    if (hist[t] > 0) atomicAdd(&bins[t], hist[t]);
}

// ---------------------------------------------------------------------------
// K3: scatter-add of normalized x into sums, LDS slab [256 clusters][64 coords]
// grid (32 point-chunks, 4 coord-chunks) x 256 thr.
__global__ __launch_bounds__(256) void k_scatter(const float* __restrict__ x,
                                                 const int* __restrict__ buckets,
                                                 const float* __restrict__ inv_norm,
                                                 float* __restrict__ sums) {
    __shared__ float acc[256 * 64];   // exactly 64KB
    int t = threadIdx.x;
    for (int i = t; i < 256 * 64; i += 256) acc[i] = 0.0f;
    __syncthreads();
    int co = t & 63, pg = t >> 6;
    int c0 = blockIdx.y * 64;
    int n0 = blockIdx.x * 2048;
    for (int i = 0; i < 512; i++) {
        int n = n0 + i * 4 + pg;                 // wave-uniform point
        int b = buckets[n] & 255;                // safety mask
        float w = inv_norm[n];
        float v = x[(size_t)n * DD + c0 + co] * w;
        atomicAdd(&acc[b * 64 + co], v);         // conflict-free ds_add
    }
    __syncthreads();
    for (int k = 0; k < 64; k++) {
        int flat = k * 256 + t;
        atomicAdd(&sums[(flat >> 6) * DD + c0 + (flat & 63)], acc[flat]);
    }
}

// ---------------------------------------------------------------------------
// K4: x_global = l2norm(sums) or old normalized mean if bin empty. f32 out.
__global__ __launch_bounds__(256) void k_xglobal(const float* __restrict__ sums,
                                                 const int* __restrict__ bins,
                                                 const float* __restrict__ means_n,
                                                 float* __restrict__ xg,
                                                 float* __restrict__ out) {
    __shared__ float red[256];
    int c = blockIdx.x, t = threadIdx.x;
    float s = sums[c * DD + t];
    red[t] = s * s;
    __syncthreads();
    for (int off = 128; off > 0; off >>= 1) {
        if (t < off) red[t] += red[t + off];
        __syncthreads();
    }
    float g;
    if (bins[c] > 0) g = s / fmaxf(sqrtf(red[0]), 1e-12f);
    else             g = means_n[c * DD + t];
    xg[c * DD + t] = g;
    out[131072 + c * DD + t] = g;   // output 2: x_global (f32)
}

// ---------------------------------------------------------------------------
// K5: k = xg @ Wk^T, v = xg @ Wv^T, written in [h][c][dh] layout (f32).
__global__ __launch_bounds__(256) void k_kv(const float* __restrict__ xg,
                                            const float* __restrict__ Wk,
                                            const float* __restrict__ Wv,
                                            float* __restrict__ out) {
    __shared__ __align__(16) float xr[256];
    int c = blockIdx.x, t = threadIdx.x;
    xr[t] = xg[c * DD + t];
    __syncthreads();
    float ak = 0.f, av = 0.f;
    const float4* wk4 = (const float4*)(Wk + (size_t)t * DD);
    const float4* wv4 = (const float4*)(Wv + (size_t)t * DD);
    for (int j4 = 0; j4 < 64; j4++) {
        float4 kk = wk4[j4];
        float4 vv = wv4[j4];
        float4 a = *(const float4*)(xr + j4 * 4);
        ak += a.x * kk.x + a.y * kk.y + a.z * kk.z + a.w * kk.w;
        av += a.x * vv.x + a.y * vv.y + a.z * vv.z + a.w * vv.w;
    }
    int h = t >> 5, dh = t & 31;
    out[h * 8192 + c * 32 + dh]         = ak;   // output 0: k (f32)
    out[65536 + h * 8192 + c * 32 + dh] = av;   // output 1: v (f32)
}

// ---------------------------------------------------------------------------
extern "C" void kernel_launch(void* const* d_in, const int* in_sizes, int n_in,
                              void* d_out, int out_size, void* d_ws, size_t ws_size,
                              hipStream_t stream) {
    (void)in_sizes; (void)n_in; (void)out_size; (void)ws_size;
    const float* x  = (const float*)d_in[0];  // [16,4096,256] f32
    const float* xm = (const float*)d_in[1];  // [256,256] f32
    const float* Wk = (const float*)d_in[2];  // [256,256] f32
    const float* Wv = (const float*)d_in[3];  // [256,256] f32

    float* ws       = (float*)d_ws;
    float* means_n  = ws;                    // 65536 f32
    float* inv_norm = ws + 65536;            // 65536 f32
    int*   buckets  = (int*)(ws + 131072);   // 65536 int
    float* sums     = ws + 196608;           // 65536 f32
    int*   bins     = (int*)(ws + 262144);   // 256 int
    float* xg       = ws + 262400;           // 65536 f32
    float* out      = (float*)d_out;

    k_prep   <<<256,  256, 0, stream>>>(xm, means_n, sums, bins);
    k_assign <<<1024, 256, 0, stream>>>(x, means_n, buckets, inv_norm);
    k_bins   <<<32,   256, 0, stream>>>(buckets, bins);
    k_scatter<<<dim3(32, 4), 256, 0, stream>>>(x, buckets, inv_norm, sums);
    k_xglobal<<<256,  256, 0, stream>>>(sums, bins, means_n, xg, out);
    k_kv     <<<256,  256, 0, stream>>>(xg, Wk, Wv, out);
}

// Round 5
// 325.373 us; speedup vs baseline: 2.2790x; 2.2790x over previous
//
#include <hip/hip_runtime.h>
#include <hip/hip_bf16.h>
#include <stdint.h>

// Problem constants (b=16, l=4096, d=256, c=256, qk_dim=256, heads=8)
// Inputs: float32. Outputs: FLOAT32:
//   out[0..65536)       k  [8,256,32]
//   out[65536..131072)  v  [8,256,32]
//   out[131072..196608) x_global [256,256]
#define DD 256
#define CC 256

typedef __attribute__((ext_vector_type(8))) short bf16x8;
typedef __attribute__((ext_vector_type(4))) float f32x4;

// round-to-nearest-even f32 -> bf16; also returns the rounded value as f32
__device__ __forceinline__ unsigned short bf16_rn(float v, float& hval) {
    unsigned u = __builtin_bit_cast(unsigned, v);
    unsigned r = u + 0x7FFFu + ((u >> 16) & 1u);
    hval = __builtin_bit_cast(float, r & 0xFFFF0000u);
    return (unsigned short)(r >> 16);
}

// ---------------------------------------------------------------------------
// K1: normalize cluster means (f32) + emit split-bf16 (hi/lo); zero sums+bins
__global__ __launch_bounds__(256) void k_prep(const float* __restrict__ xm,
                                              float* __restrict__ means_n,
                                              unsigned short* __restrict__ mh,
                                              unsigned short* __restrict__ ml,
                                              float* __restrict__ sums,
                                              int* __restrict__ bins) {
    __shared__ float red[256];
    int c = blockIdx.x, t = threadIdx.x;
    float v = xm[c * DD + t];
    red[t] = v * v;
    __syncthreads();
    for (int off = 128; off > 0; off >>= 1) {
        if (t < off) red[t] += red[t + off];
        __syncthreads();
    }
    float inv = 1.0f / fmaxf(sqrtf(red[0]), 1e-12f);
    float vn = v * inv;
    means_n[c * DD + t] = vn;
    float hf; unsigned short hb = bf16_rn(vn, hf);
    float lo = vn - hf;                 // exact
    float d2; unsigned short lb = bf16_rn(lo, d2);
    mh[c * DD + t] = hb;
    ml[c * DD + t] = lb;
    sums[c * DD + t] = 0.0f;
    if (c == 0) bins[t] = 0;
}

// ---------------------------------------------------------------------------
// K2: MFMA similarity + argmax + row inv-norm. No LDS.
// Wave w owns points p0..p0+15 (p0 = blk*64 + w*16). Per k-chunk (K=32):
// lane (q=lane>>4, m=lane&15) loads x[p0+m][kc*32+q*8 .. +7] (two float4,
// 128B-coalesced per row), splits to bf16 hi/lo A-frags; B-frags stream from
// global mh/ml (512KB, L1/L2 resident). dists = x.means^T via 3 MFMAs
// (hh, lh, hl) exact to ~2^-18. C/D layout: cluster=ct*16+(lane&15),
// point=p0+q*4+reg [guide §3, m89-verified].
__global__ __launch_bounds__(256, 3) void k_assign(
        const float* __restrict__ x,
        const unsigned short* __restrict__ mh,
        const unsigned short* __restrict__ ml,
        int* __restrict__ buckets,
        float* __restrict__ inv_norm) {
    int t = threadIdx.x;
    int w = t >> 6, lane = t & 63;
    int m = lane & 15, q = lane >> 4;          // q in 0..3
    int p0 = blockIdx.x * 64 + w * 16;
    const float* xrow = x + (size_t)(p0 + m) * DD;

    f32x4 acc[16];
#pragma unroll
    for (int ct = 0; ct < 16; ct++) acc[ct] = (f32x4){0.f, 0.f, 0.f, 0.f};
    float ssl = 0.f;

    for (int kc = 0; kc < 8; kc++) {
        int koff = kc * 32 + q * 8;
        float4 xa = *(const float4*)(xrow + koff);
        float4 xb = *(const float4*)(xrow + koff + 4);
        ssl += xa.x * xa.x + xa.y * xa.y + xa.z * xa.z + xa.w * xa.w +
               xb.x * xb.x + xb.y * xb.y + xb.z * xb.z + xb.w * xb.w;
        float xv[8] = {xa.x, xa.y, xa.z, xa.w, xb.x, xb.y, xb.z, xb.w};
        bf16x8 ah, al;
#pragma unroll
        for (int j = 0; j < 8; j++) {
            float hf; unsigned short hb = bf16_rn(xv[j], hf);
            float lo = xv[j] - hf;             // exact
            float d2; unsigned short lb = bf16_rn(lo, d2);
            ah[j] = (short)hb;
            al[j] = (short)lb;
        }
#pragma unroll
        for (int ct = 0; ct < 16; ct++) {
            size_t mo = (size_t)((ct * 16 + m) * DD + koff);
            bf16x8 bh = *(const bf16x8*)(mh + mo);
            bf16x8 bl = *(const bf16x8*)(ml + mo);
            acc[ct] = __builtin_amdgcn_mfma_f32_16x16x32_bf16(ah, bh, acc[ct], 0, 0, 0);
            acc[ct] = __builtin_amdgcn_mfma_f32_16x16x32_bf16(al, bh, acc[ct], 0, 0, 0);
            acc[ct] = __builtin_amdgcn_mfma_f32_16x16x32_bf16(ah, bl, acc[ct], 0, 0, 0);
        }
    }

    // row inv-norm: lane covers 64 dims; partners differ in bits 4,5 of lane
    ssl += __shfl_xor(ssl, 16, 64);
    ssl += __shfl_xor(ssl, 32, 64);
    if (q == 0) inv_norm[p0 + m] = 1.0f / fmaxf(sqrtf(ssl), 1e-12f);

    // per-lane argmax: lane holds points p0+q*4+r (r=reg) x clusters ct*16+m
    float bv[4]; int bi[4];
#pragma unroll
    for (int r = 0; r < 4; r++) {
        bv[r] = acc[0][r]; bi[r] = m;          // ct=0 -> cluster m
#pragma unroll
        for (int ct = 1; ct < 16; ct++) {
            float v2 = acc[ct][r];
            if (v2 > bv[r]) { bv[r] = v2; bi[r] = ct * 16 + m; }
        }
    }
    // reduce across the 16 m-lanes (same q); tie -> lowest cluster index
#pragma unroll
    for (int mask = 1; mask < 16; mask <<= 1) {
#pragma unroll
        for (int r = 0; r < 4; r++) {
            float ov = __shfl_xor(bv[r], mask, 64);
            int   oi = __shfl_xor(bi[r], mask, 64);
            if (ov > bv[r] || (ov == bv[r] && oi < bi[r])) { bv[r] = ov; bi[r] = oi; }
        }
    }
    if (m == 0) {
#pragma unroll
        for (int r = 0; r < 4; r++) buckets[p0 + q * 4 + r] = bi[r];
    }
}

// ---------------------------------------------------------------------------
// K3b: bin counts (histogram of buckets). grid 32 blocks x 256 thr.
__global__ __launch_bounds__(256) void k_bins(const int* __restrict__ buckets,
                                              int* __restrict__ bins) {
    __shared__ int hist[256];
    int t = threadIdx.x;
    hist[t] = 0;
    __syncthreads();
    int n0 = blockIdx.x * 2048;
    for (int i = 0; i < 8; i++)
        atomicAdd(&hist[buckets[n0 + i * 256 + t] & 255], 1);
    __syncthreads();
    if (hist[t] > 0) atomicAdd(&bins[t], hist[t]);
}

// ---------------------------------------------------------------------------
// K3: scatter-add of normalized x into sums. LDS slab [256 clusters][32 coords]
// = 32KB (5 blocks/CU). grid (32 point-chunks, 8 coord-chunks) = 256 blocks.
// Wave = 2 points x 32 coords -> 2-way LDS banking (free).
__global__ __launch_bounds__(256) void k_scatter(const float* __restrict__ x,
                                                 const int* __restrict__ buckets,
                                                 const float* __restrict__ inv_norm,
                                                 float* __restrict__ sums) {
    __shared__ float acc[256 * 32];   // 32KB
    int t = threadIdx.x;
    for (int i = t; i < 256 * 32; i += 256) acc[i] = 0.0f;
    __syncthreads();
    int co = t & 31, pg = t >> 5;               // 8 point-groups
    int c0 = blockIdx.y * 32;
    int n0 = blockIdx.x * 2048;
    for (int i = 0; i < 256; i++) {
        int n = n0 + i * 8 + pg;
        int b = buckets[n] & 255;
        float wgt = inv_norm[n];
        float v = x[(size_t)n * DD + c0 + co] * wgt;
        atomicAdd(&acc[b * 32 + co], v);
    }
    __syncthreads();
    for (int k = 0; k < 32; k++) {
        int flat = k * 256 + t;
        atomicAdd(&sums[(flat >> 5) * DD + c0 + (flat & 31)], acc[flat]);
    }
}

// ---------------------------------------------------------------------------
// K4: x_global = l2norm(sums) or old normalized mean if bin empty. f32 out.
__global__ __launch_bounds__(256) void k_xglobal(const float* __restrict__ sums,
                                                 const int* __restrict__ bins,
                                                 const float* __restrict__ means_n,
                                                 float* __restrict__ xg,
                                                 float* __restrict__ out) {
    __shared__ float red[256];
    int c = blockIdx.x, t = threadIdx.x;
    float s = sums[c * DD + t];
    red[t] = s * s;
    __syncthreads();
    for (int off = 128; off > 0; off >>= 1) {
        if (t < off) red[t] += red[t + off];
        __syncthreads();
    }
    float g;
    if (bins[c] > 0) g = s / fmaxf(sqrtf(red[0]), 1e-12f);
    else             g = means_n[c * DD + t];
    xg[c * DD + t] = g;
    out[131072 + c * DD + t] = g;   // output 2: x_global (f32)
}

// ---------------------------------------------------------------------------
// K5: k = xg @ Wk^T, v = xg @ Wv^T in [h][c][dh] layout (f32).
// grid 64 blocks x 4 clusters: W rows read once per block (32MB L2 total).
__global__ __launch_bounds__(256) void k_kv(const float* __restrict__ xg,
                                            const float* __restrict__ Wk,
                                            const float* __restrict__ Wv,
                                            float* __restrict__ out) {
    __shared__ __align__(16) float xr[4][256];
    int t = threadIdx.x;
    int cg = blockIdx.x * 4;
#pragma unroll
    for (int c = 0; c < 4; c++) xr[c][t] = xg[(cg + c) * DD + t];
    __syncthreads();
    float ak[4] = {0.f, 0.f, 0.f, 0.f}, av[4] = {0.f, 0.f, 0.f, 0.f};
    const float4* wkp = (const float4*)(Wk + (size_t)t * DD);
    const float4* wvp = (const float4*)(Wv + (size_t)t * DD);
    for (int j4 = 0; j4 < 64; j4++) {
        float4 wk = wkp[j4], wv = wvp[j4];
#pragma unroll
        for (int c = 0; c < 4; c++) {
            float4 a = *(const float4*)&xr[c][j4 * 4];
            ak[c] += a.x * wk.x + a.y * wk.y + a.z * wk.z + a.w * wk.w;
            av[c] += a.x * wv.x + a.y * wv.y + a.z * wv.z + a.w * wv.w;
        }
    }
    int h = t >> 5, dh = t & 31;
#pragma unroll
    for (int c = 0; c < 4; c++) {
        out[h * 8192 + (cg + c) * 32 + dh]         = ak[c];   // k
        out[65536 + h * 8192 + (cg + c) * 32 + dh] = av[c];   // v
    }
}

// ---------------------------------------------------------------------------
extern "C" void kernel_launch(void* const* d_in, const int* in_sizes, int n_in,
                              void* d_out, int out_size, void* d_ws, size_t ws_size,
                              hipStream_t stream) {
    (void)in_sizes; (void)n_in; (void)out_size; (void)ws_size;
    const float* x  = (const float*)d_in[0];  // [16,4096,256] f32
    const float* xm = (const float*)d_in[1];  // [256,256] f32
    const float* Wk = (const float*)d_in[2];  // [256,256] f32
    const float* Wv = (const float*)d_in[3];  // [256,256] f32

    float* ws       = (float*)d_ws;
    float* means_n  = ws;                     // 65536 f32
    float* inv_norm = ws + 65536;             // 65536 f32
    int*   buckets  = (int*)(ws + 131072);    // 65536 int
    float* sums     = ws + 196608;            // 65536 f32
    int*   bins     = (int*)(ws + 262144);    // 256 int
    float* xg       = ws + 262400;            // 65536 f32
    unsigned short* mh = (unsigned short*)(ws + 327936);  // 65536 bf16
    unsigned short* ml = (unsigned short*)(ws + 360704);  // 65536 bf16
    float* out      = (float*)d_out;

    k_prep   <<<256,  256, 0, stream>>>(xm, means_n, mh, ml, sums, bins);
    k_assign <<<1024, 256, 0, stream>>>(x, mh, ml, buckets, inv_norm);
    k_bins   <<<32,   256, 0, stream>>>(buckets, bins);
    k_scatter<<<dim3(32, 8), 256, 0, stream>>>(x, buckets, inv_norm, sums);
    k_xglobal<<<256,  256, 0, stream>>>(sums, bins, means_n, xg, out);
    k_kv     <<<64,   256, 0, stream>>>(xg, Wk, Wv, out);
}

// Round 6
// 306.325 us; speedup vs baseline: 2.4207x; 1.0622x over previous
//
#include <hip/hip_runtime.h>
#include <hip/hip_bf16.h>
#include <stdint.h>

// Problem constants (b=16, l=4096, d=256, c=256, qk_dim=256, heads=8)
// Inputs: float32. Outputs: FLOAT32:
//   out[0..65536)       k  [8,256,32]
//   out[65536..131072)  v  [8,256,32]
//   out[131072..196608) x_global [256,256]
#define DD 256
#define CC 256

typedef __attribute__((ext_vector_type(8))) short bf16x8;
typedef __attribute__((ext_vector_type(4))) float f32x4;

// round-to-nearest-even f32 -> bf16; also returns the rounded value as f32
__device__ __forceinline__ unsigned short bf16_rn(float v, float& hval) {
    unsigned u = __builtin_bit_cast(unsigned, v);
    unsigned r = u + 0x7FFFu + ((u >> 16) & 1u);
    hval = __builtin_bit_cast(float, r & 0xFFFF0000u);
    return (unsigned short)(r >> 16);
}

// ---------------------------------------------------------------------------
// K1: normalize cluster means (f32); emit packed split-bf16 slices for the
// MFMA kernel: mpk[kc(8)][ hi: [q(4)][c(256)][8] | lo: same ] (32KB per kc,
// contiguous -> global_load_lds friendly). Zero sums + bins.
__global__ __launch_bounds__(256) void k_prep(const float* __restrict__ xm,
                                              float* __restrict__ means_n,
                                              unsigned short* __restrict__ mpk,
                                              float* __restrict__ sums,
                                              int* __restrict__ bins) {
    __shared__ float red[256];
    int c = blockIdx.x, t = threadIdx.x;
    float v = xm[c * DD + t];
    red[t] = v * v;
    __syncthreads();
    for (int off = 128; off > 0; off >>= 1) {
        if (t < off) red[t] += red[t + off];
        __syncthreads();
    }
    float inv = 1.0f / fmaxf(sqrtf(red[0]), 1e-12f);
    float vn = v * inv;
    means_n[c * DD + t] = vn;
    float hf; unsigned short hb = bf16_rn(vn, hf);
    float lo = vn - hf;                 // exact
    float d2; unsigned short lb = bf16_rn(lo, d2);
    int kc = t >> 5, q = (t >> 3) & 3, j = t & 7;
    mpk[kc * 16384 + q * 2048 + c * 8 + j]        = hb;
    mpk[kc * 16384 + 8192 + q * 2048 + c * 8 + j] = lb;
    sums[c * DD + t] = 0.0f;
    if (c == 0) bins[t] = 0;
}

// ---------------------------------------------------------------------------
// K2: MFMA similarity + argmax + row inv-norm + bin counts.
// Block = 4 waves, each wave owns 32 points (two 16-point A-tiles sharing B).
// B (means hi/lo) staged per-kc into LDS via global_load_lds (16B wide),
// double-buffered 2x32KB. ds_read_b128 fragment reads are bank-conflict-free
// (8 dwords/bank = b128 floor). 3-MFMA split-bf16 (hh+lh+hl), exact ~2^-18.
// C/D layout: cluster=ct*16+(lane&15), point=p0+q*4+reg [m89-verified, R5-passed].
__global__ __launch_bounds__(256) void k_assign(
        const float* __restrict__ x,
        const unsigned short* __restrict__ mpk,
        int* __restrict__ buckets,
        float* __restrict__ inv_norm,
        int* __restrict__ bins) {
    __shared__ __align__(16) unsigned short mlds[2][16384];   // 2 x 32KB
    int t = threadIdx.x;
    int w = t >> 6, lane = t & 63;
    int m = lane & 15, q = lane >> 4;          // q in 0..3
    int p0 = blockIdx.x * 128 + w * 32;
    const float* xrow0 = x + (size_t)(p0 + m) * DD;
    const float* xrow1 = xrow0 + 16 * DD;

    f32x4 acc0[16], acc1[16];
#pragma unroll
    for (int ct = 0; ct < 16; ct++) {
        acc0[ct] = (f32x4){0.f, 0.f, 0.f, 0.f};
        acc1[ct] = (f32x4){0.f, 0.f, 0.f, 0.f};
    }
    float ss0 = 0.f, ss1 = 0.f;

    // stage kc slice: 32KB/block, 8KB/wave = 8 x (64 lanes x 16B)
#define STAGE(KC, BUF) do {                                                     \
        const unsigned short* gsrc = mpk + (KC) * 16384 + w * 4096 + lane * 8;  \
        unsigned short* lb = &mlds[BUF][w * 4096];                              \
        _Pragma("unroll")                                                       \
        for (int i = 0; i < 8; i++)                                             \
            __builtin_amdgcn_global_load_lds(                                   \
                (const __attribute__((address_space(1))) void*)(gsrc + i * 512),\
                (__attribute__((address_space(3))) void*)(lb + i * 512),        \
                16, 0, 0);                                                      \
    } while (0)

    STAGE(0, 0);
    __syncthreads();

    for (int kc = 0; kc < 8; kc++) {
        int cur = kc & 1;
        if (kc < 7) STAGE(kc + 1, cur ^ 1);

        int koff = kc * 32 + q * 8;
        float4 xa0 = *(const float4*)(xrow0 + koff);
        float4 xb0 = *(const float4*)(xrow0 + koff + 4);
        float4 xa1 = *(const float4*)(xrow1 + koff);
        float4 xb1 = *(const float4*)(xrow1 + koff + 4);
        ss0 += xa0.x * xa0.x + xa0.y * xa0.y + xa0.z * xa0.z + xa0.w * xa0.w +
               xb0.x * xb0.x + xb0.y * xb0.y + xb0.z * xb0.z + xb0.w * xb0.w;
        ss1 += xa1.x * xa1.x + xa1.y * xa1.y + xa1.z * xa1.z + xa1.w * xa1.w +
               xb1.x * xb1.x + xb1.y * xb1.y + xb1.z * xb1.z + xb1.w * xb1.w;

        float xv0[8] = {xa0.x, xa0.y, xa0.z, xa0.w, xb0.x, xb0.y, xb0.z, xb0.w};
        float xv1[8] = {xa1.x, xa1.y, xa1.z, xa1.w, xb1.x, xb1.y, xb1.z, xb1.w};
        bf16x8 ah0, al0, ah1, al1;
#pragma unroll
        for (int j = 0; j < 8; j++) {
            float hf; unsigned short hb = bf16_rn(xv0[j], hf);
            float lo = xv0[j] - hf; float d2;
            al0[j] = (short)bf16_rn(lo, d2); ah0[j] = (short)hb;
            hb = bf16_rn(xv1[j], hf);
            lo = xv1[j] - hf;
            al1[j] = (short)bf16_rn(lo, d2); ah1[j] = (short)hb;
        }

        const unsigned short* fb = &mlds[cur][q * 2048 + m * 8];
#pragma unroll
        for (int ct = 0; ct < 16; ct++) {
            bf16x8 bh = *(const bf16x8*)(fb + ct * 128);
            bf16x8 bl = *(const bf16x8*)(fb + 8192 + ct * 128);
            acc0[ct] = __builtin_amdgcn_mfma_f32_16x16x32_bf16(ah0, bh, acc0[ct], 0, 0, 0);
            acc0[ct] = __builtin_amdgcn_mfma_f32_16x16x32_bf16(al0, bh, acc0[ct], 0, 0, 0);
            acc0[ct] = __builtin_amdgcn_mfma_f32_16x16x32_bf16(ah0, bl, acc0[ct], 0, 0, 0);
            acc1[ct] = __builtin_amdgcn_mfma_f32_16x16x32_bf16(ah1, bh, acc1[ct], 0, 0, 0);
            acc1[ct] = __builtin_amdgcn_mfma_f32_16x16x32_bf16(al1, bh, acc1[ct], 0, 0, 0);
            acc1[ct] = __builtin_amdgcn_mfma_f32_16x16x32_bf16(ah1, bl, acc1[ct], 0, 0, 0);
        }
        __syncthreads();   // drains staged vmcnt + all lgkm before buffer reuse
    }
#undef STAGE

    // row inv-norms: sum over the 4 q-lane groups (lane bits 4,5)
    ss0 += __shfl_xor(ss0, 16, 64); ss0 += __shfl_xor(ss0, 32, 64);
    ss1 += __shfl_xor(ss1, 16, 64); ss1 += __shfl_xor(ss1, 32, 64);
    if (q == 0) {
        inv_norm[p0 + m]      = 1.0f / fmaxf(sqrtf(ss0), 1e-12f);
        inv_norm[p0 + 16 + m] = 1.0f / fmaxf(sqrtf(ss1), 1e-12f);
    }

    // argmax: per-lane over ascending ct (strict > keeps lowest cluster)
    float bv0[4], bv1[4]; int bi0[4], bi1[4];
#pragma unroll
    for (int r = 0; r < 4; r++) {
        bv0[r] = acc0[0][r]; bi0[r] = m;
        bv1[r] = acc1[0][r]; bi1[r] = m;
#pragma unroll
        for (int ct = 1; ct < 16; ct++) {
            float v2 = acc0[ct][r];
            if (v2 > bv0[r]) { bv0[r] = v2; bi0[r] = ct * 16 + m; }
            float v3 = acc1[ct][r];
            if (v3 > bv1[r]) { bv1[r] = v3; bi1[r] = ct * 16 + m; }
        }
    }
    // reduce across the 16 m-lanes; tie -> lowest cluster index
#pragma unroll
    for (int mask = 1; mask < 16; mask <<= 1) {
#pragma unroll
        for (int r = 0; r < 4; r++) {
            float ov = __shfl_xor(bv0[r], mask, 64);
            int   oi = __shfl_xor(bi0[r], mask, 64);
            if (ov > bv0[r] || (ov == bv0[r] && oi < bi0[r])) { bv0[r] = ov; bi0[r] = oi; }
            ov = __shfl_xor(bv1[r], mask, 64);
            oi = __shfl_xor(bi1[r], mask, 64);
            if (ov > bv1[r] || (ov == bv1[r] && oi < bi1[r])) { bv1[r] = ov; bi1[r] = oi; }
        }
    }
    if (m == 0) {
#pragma unroll
        for (int r = 0; r < 4; r++) {
            buckets[p0 + q * 4 + r] = bi0[r];
            atomicAdd(&bins[bi0[r]], 1);
            buckets[p0 + 16 + q * 4 + r] = bi1[r];
            atomicAdd(&bins[bi1[r]], 1);
        }
    }
}

// ---------------------------------------------------------------------------
// K3: scatter-add of normalized x into sums. LDS slab [256 clusters][32 coords]
// = 32KB. grid (64 point-chunks, 8 coord-chunks) = 512 blocks (2/CU).
__global__ __launch_bounds__(256) void k_scatter(const float* __restrict__ x,
                                                 const int* __restrict__ buckets,
                                                 const float* __restrict__ inv_norm,
                                                 float* __restrict__ sums) {
    __shared__ float acc[256 * 32];   // 32KB
    int t = threadIdx.x;
    for (int i = t; i < 256 * 32; i += 256) acc[i] = 0.0f;
    __syncthreads();
    int co = t & 31, pg = t >> 5;               // 8 point-groups
    int c0 = blockIdx.y * 32;
    int n0 = blockIdx.x * 1024;
    for (int i = 0; i < 128; i++) {
        int n = n0 + i * 8 + pg;
        int b = buckets[n] & 255;
        float wgt = inv_norm[n];
        float v = x[(size_t)n * DD + c0 + co] * wgt;
        atomicAdd(&acc[b * 32 + co], v);
    }
    __syncthreads();
    for (int k = 0; k < 32; k++) {
        int flat = k * 256 + t;
        atomicAdd(&sums[(flat >> 5) * DD + c0 + (flat & 31)], acc[flat]);
    }
}

// ---------------------------------------------------------------------------
// K4: x_global = l2norm(sums) or old normalized mean if bin empty. f32 out.
__global__ __launch_bounds__(256) void k_xglobal(const float* __restrict__ sums,
                                                 const int* __restrict__ bins,
                                                 const float* __restrict__ means_n,
                                                 float* __restrict__ xg,
                                                 float* __restrict__ out) {
    __shared__ float red[256];
    int c = blockIdx.x, t = threadIdx.x;
    float s = sums[c * DD + t];
    red[t] = s * s;
    __syncthreads();
    for (int off = 128; off > 0; off >>= 1) {
        if (t < off) red[t] += red[t + off];
        __syncthreads();
    }
    float g;
    if (bins[c] > 0) g = s / fmaxf(sqrtf(red[0]), 1e-12f);
    else             g = means_n[c * DD + t];
    xg[c * DD + t] = g;
    out[131072 + c * DD + t] = g;   // output 2: x_global (f32)
}

// ---------------------------------------------------------------------------
// K5: k = xg @ Wk^T, v = xg @ Wv^T in [h][c][dh] layout (f32).
// grid 256 blocks (1 cluster each): full CU coverage; W traffic 128MB from L2.
__global__ __launch_bounds__(256) void k_kv(const float* __restrict__ xg,
                                            const float* __restrict__ Wk,
                                            const float* __restrict__ Wv,
                                            float* __restrict__ out) {
    __shared__ __align__(16) float xr[256];
    int c = blockIdx.x, t = threadIdx.x;
    xr[t] = xg[c * DD + t];
    __syncthreads();
    float ak = 0.f, av = 0.f;
    const float4* wkp = (const float4*)(Wk + (size_t)t * DD);
    const float4* wvp = (const float4*)(Wv + (size_t)t * DD);
#pragma unroll 8
    for (int j4 = 0; j4 < 64; j4++) {
        float4 wk = wkp[j4], wv = wvp[j4];
        float4 a = *(const float4*)(xr + j4 * 4);
        ak += a.x * wk.x + a.y * wk.y + a.z * wk.z + a.w * wk.w;
        av += a.x * wv.x + a.y * wv.y + a.z * wv.z + a.w * wv.w;
    }
    int h = t >> 5, dh = t & 31;
    out[h * 8192 + c * 32 + dh]         = ak;   // k
    out[65536 + h * 8192 + c * 32 + dh] = av;   // v
}

// ---------------------------------------------------------------------------
extern "C" void kernel_launch(void* const* d_in, const int* in_sizes, int n_in,
                              void* d_out, int out_size, void* d_ws, size_t ws_size,
                              hipStream_t stream) {
    (void)in_sizes; (void)n_in; (void)out_size; (void)ws_size;
    const float* x  = (const float*)d_in[0];  // [16,4096,256] f32
    const float* xm = (const float*)d_in[1];  // [256,256] f32
    const float* Wk = (const float*)d_in[2];  // [256,256] f32
    const float* Wv = (const float*)d_in[3];  // [256,256] f32

    float* ws       = (float*)d_ws;
    float* means_n  = ws;                     // 65536 f32
    float* inv_norm = ws + 65536;             // 65536 f32
    int*   buckets  = (int*)(ws + 131072);    // 65536 int
    float* sums     = ws + 196608;            // 65536 f32
    int*   bins     = (int*)(ws + 262144);    // 256 int
    float* xg       = ws + 262400;            // 65536 f32
    unsigned short* mpk = (unsigned short*)(ws + 327936);  // 131072 bf16 (256KB)
    float* out      = (float*)d_out;

    k_prep   <<<256, 256, 0, stream>>>(xm, means_n, mpk, sums, bins);
    k_assign <<<512, 256, 0, stream>>>(x, mpk, buckets, inv_norm, bins);
    k_scatter<<<dim3(64, 8), 256, 0, stream>>>(x, buckets, inv_norm, sums);
    k_xglobal<<<256, 256, 0, stream>>>(sums, bins, means_n, xg, out);
    k_kv     <<<256, 256, 0, stream>>>(xg, Wk, Wv, out);
}

// Round 7
// 293.491 us; speedup vs baseline: 2.5266x; 1.0437x over previous
//
#include <hip/hip_runtime.h>
#include <hip/hip_bf16.h>
#include <stdint.h>

// Problem constants (b=16, l=4096, d=256, c=256, qk_dim=256, heads=8)
// Inputs: float32. Outputs: FLOAT32:
//   out[0..65536)       k  [8,256,32]
//   out[65536..131072)  v  [8,256,32]
//   out[131072..196608) x_global [256,256]
#define DD 256
#define CC 256

typedef __attribute__((ext_vector_type(8))) short bf16x8;
typedef __attribute__((ext_vector_type(4))) float f32x4;

// round-to-nearest-even f32 -> bf16; also returns the rounded value as f32
__device__ __forceinline__ unsigned short bf16_rn(float v, float& hval) {
    unsigned u = __builtin_bit_cast(unsigned, v);
    unsigned r = u + 0x7FFFu + ((u >> 16) & 1u);
    hval = __builtin_bit_cast(float, r & 0xFFFF0000u);
    return (unsigned short)(r >> 16);
}

// ---------------------------------------------------------------------------
// K1: normalize cluster means (f32); emit packed split-bf16 slices:
// mpk[kc(8)][ hi: [q(4)][c(256)][8] | lo: same ] (32KB per kc slice,
// contiguous for global_load_lds). Zero sums + bins.
__global__ __launch_bounds__(256) void k_prep(const float* __restrict__ xm,
                                              float* __restrict__ means_n,
                                              unsigned short* __restrict__ mpk,
                                              float* __restrict__ sums,
                                              int* __restrict__ bins) {
    __shared__ float red[256];
    int c = blockIdx.x, t = threadIdx.x;
    float v = xm[c * DD + t];
    red[t] = v * v;
    __syncthreads();
    for (int off = 128; off > 0; off >>= 1) {
        if (t < off) red[t] += red[t + off];
        __syncthreads();
    }
    float inv = 1.0f / fmaxf(sqrtf(red[0]), 1e-12f);
    float vn = v * inv;
    means_n[c * DD + t] = vn;
    float hf; unsigned short hb = bf16_rn(vn, hf);
    float lo = vn - hf;                 // exact
    float d2; unsigned short lb = bf16_rn(lo, d2);
    int kc = t >> 5, q = (t >> 3) & 3, j = t & 7;
    mpk[kc * 16384 + q * 2048 + c * 8 + j]        = hb;
    mpk[kc * 16384 + 8192 + q * 2048 + c * 8 + j] = lb;
    sums[c * DD + t] = 0.0f;
    if (c == 0) bins[t] = 0;
}

// ---------------------------------------------------------------------------
// K2 v3: MFMA similarity + argmax + inv-norm + bins.
// OCCUPANCY IS THE LEVER (R6 lesson: 2 A-tiles = 268 unified regs = 1
// wave/SIMD = 9% occupancy = all pipes idle). v3: 16 points/wave ->
// acc = 64 AGPR; launch_bounds(256,3) caps unified regs at 170 -> 3 waves/
// SIMD; single 32KB LDS buffer -> 4 blocks/CU resident; cross-block overlap
// hides the stage barriers (m114). x row loads prefetched one kc ahead.
// 3-MFMA split-bf16 (hh+lh+hl), exact ~2^-18 (R5/R6-proven identical absmax).
// C/D layout: cluster=ct*16+(lane&15), point=p0+q*4+reg.
__global__ __launch_bounds__(256, 3) void k_assign(
        const float* __restrict__ x,
        const unsigned short* __restrict__ mpk,
        int* __restrict__ buckets,
        float* __restrict__ inv_norm,
        int* __restrict__ bins) {
    __shared__ __align__(16) unsigned short mlds[16384];   // 32KB, one kc slice
    int t = threadIdx.x;
    int w = t >> 6, lane = t & 63;
    int m = lane & 15, q = lane >> 4;          // q in 0..3
    int p0 = blockIdx.x * 64 + w * 16;
    const float* xq = x + (size_t)(p0 + m) * DD + q * 8;

    f32x4 acc[16];
#pragma unroll
    for (int ct = 0; ct < 16; ct++) acc[ct] = (f32x4){0.f, 0.f, 0.f, 0.f};
    float ss = 0.f;

    // stage kc slice: 32KB/block, 8KB/wave = 8 x (64 lanes x 16B)
#define STAGE(KC) do {                                                          \
        const unsigned short* gsrc = mpk + (KC) * 16384 + w * 4096 + lane * 8;  \
        unsigned short* lb = mlds + w * 4096;                                   \
        _Pragma("unroll")                                                       \
        for (int i = 0; i < 8; i++)                                             \
            __builtin_amdgcn_global_load_lds(                                   \
                (const __attribute__((address_space(1))) void*)(gsrc + i * 512),\
                (__attribute__((address_space(3))) void*)(lb + i * 512),        \
                16, 0, 0);                                                      \
    } while (0)

    STAGE(0);
    float4 nxa = *(const float4*)(xq);
    float4 nxb = *(const float4*)(xq + 4);

    for (int kc = 0; kc < 8; kc++) {
        __syncthreads();   // stage(kc) landed (barrier drains vmcnt)

        float4 xa = nxa, xb = nxb;
        ss += xa.x * xa.x + xa.y * xa.y + xa.z * xa.z + xa.w * xa.w +
              xb.x * xb.x + xb.y * xb.y + xb.z * xb.z + xb.w * xb.w;
        float xv[8] = {xa.x, xa.y, xa.z, xa.w, xb.x, xb.y, xb.z, xb.w};
        bf16x8 ah, al;
#pragma unroll
        for (int j = 0; j < 8; j++) {
            float hf; unsigned short hb = bf16_rn(xv[j], hf);
            float lo = xv[j] - hf; float d2;
            al[j] = (short)bf16_rn(lo, d2); ah[j] = (short)hb;
        }
        if (kc < 7) {   // prefetch next x chunk under the MFMA loop
            nxa = *(const float4*)(xq + (kc + 1) * 32);
            nxb = *(const float4*)(xq + (kc + 1) * 32 + 4);
        }

        const unsigned short* fb = mlds + q * 2048 + m * 8;
#pragma unroll
        for (int ct = 0; ct < 16; ct++) {
            bf16x8 bh = *(const bf16x8*)(fb + ct * 128);
            bf16x8 bl = *(const bf16x8*)(fb + 8192 + ct * 128);
            acc[ct] = __builtin_amdgcn_mfma_f32_16x16x32_bf16(ah, bh, acc[ct], 0, 0, 0);
            acc[ct] = __builtin_amdgcn_mfma_f32_16x16x32_bf16(al, bh, acc[ct], 0, 0, 0);
            acc[ct] = __builtin_amdgcn_mfma_f32_16x16x32_bf16(ah, bl, acc[ct], 0, 0, 0);
        }

        if (kc < 7) {
            __syncthreads();   // all waves done reading slice kc
            STAGE(kc + 1);
        }
    }
#undef STAGE

    // row inv-norm: sum over the 4 q-lane groups (lane bits 4,5)
    ss += __shfl_xor(ss, 16, 64);
    ss += __shfl_xor(ss, 32, 64);
    if (q == 0) inv_norm[p0 + m] = 1.0f / fmaxf(sqrtf(ss), 1e-12f);

    // argmax: per-lane over ascending ct (strict > keeps lowest cluster)
    float bv[4]; int bi[4];
#pragma unroll
    for (int r = 0; r < 4; r++) {
        bv[r] = acc[0][r]; bi[r] = m;
#pragma unroll
        for (int ct = 1; ct < 16; ct++) {
            float v2 = acc[ct][r];
            if (v2 > bv[r]) { bv[r] = v2; bi[r] = ct * 16 + m; }
        }
    }
    // reduce across the 16 m-lanes; tie -> lowest cluster index
#pragma unroll
    for (int mask = 1; mask < 16; mask <<= 1) {
#pragma unroll
        for (int r = 0; r < 4; r++) {
            float ov = __shfl_xor(bv[r], mask, 64);
            int   oi = __shfl_xor(bi[r], mask, 64);
            if (ov > bv[r] || (ov == bv[r] && oi < bi[r])) { bv[r] = ov; bi[r] = oi; }
        }
    }
    if (m == 0) {
#pragma unroll
        for (int r = 0; r < 4; r++) {
            buckets[p0 + q * 4 + r] = bi[r];
            atomicAdd(&bins[bi[r]], 1);
        }
    }
}

// ---------------------------------------------------------------------------
// K3: scatter-add of normalized x into sums. LDS slab [256 clusters][32 coords]
// = 32KB. grid (64 point-chunks, 8 coord-chunks) = 512 blocks (2/CU).
__global__ __launch_bounds__(256) void k_scatter(const float* __restrict__ x,
                                                 const int* __restrict__ buckets,
                                                 const float* __restrict__ inv_norm,
                                                 float* __restrict__ sums) {
    __shared__ float acc[256 * 32];   // 32KB
    int t = threadIdx.x;
    for (int i = t; i < 256 * 32; i += 256) acc[i] = 0.0f;
    __syncthreads();
    int co = t & 31, pg = t >> 5;               // 8 point-groups
    int c0 = blockIdx.y * 32;
    int n0 = blockIdx.x * 1024;
    for (int i = 0; i < 128; i++) {
        int n = n0 + i * 8 + pg;
        int b = buckets[n] & 255;
        float wgt = inv_norm[n];
        float v = x[(size_t)n * DD + c0 + co] * wgt;
        atomicAdd(&acc[b * 32 + co], v);
    }
    __syncthreads();
    for (int k = 0; k < 32; k++) {
        int flat = k * 256 + t;
        atomicAdd(&sums[(flat >> 5) * DD + c0 + (flat & 31)], acc[flat]);
    }
}

// ---------------------------------------------------------------------------
// K4+K5 fused: x_global = l2norm(sums) (or old mean if empty bin), then
// k = xg @ Wk^T, v = xg @ Wv^T in [h][c][dh] layout. All f32. 256 blocks.
__global__ __launch_bounds__(256) void k_xgkv(const float* __restrict__ sums,
                                              const int* __restrict__ bins,
                                              const float* __restrict__ means_n,
                                              const float* __restrict__ Wk,
                                              const float* __restrict__ Wv,
                                              float* __restrict__ out) {
    __shared__ float red[256];
    __shared__ __align__(16) float xr[256];
    int c = blockIdx.x, t = threadIdx.x;
    float s = sums[c * DD + t];
    red[t] = s * s;
    __syncthreads();
    for (int off = 128; off > 0; off >>= 1) {
        if (t < off) red[t] += red[t + off];
        __syncthreads();
    }
    float g;
    if (bins[c] > 0) g = s / fmaxf(sqrtf(red[0]), 1e-12f);
    else             g = means_n[c * DD + t];
    out[131072 + c * DD + t] = g;   // output 2: x_global
    xr[t] = g;
    __syncthreads();

    float ak = 0.f, av = 0.f;
    const float4* wkp = (const float4*)(Wk + (size_t)t * DD);
    const float4* wvp = (const float4*)(Wv + (size_t)t * DD);
#pragma unroll 8
    for (int j4 = 0; j4 < 64; j4++) {
        float4 wk = wkp[j4], wv = wvp[j4];
        float4 a = *(const float4*)(xr + j4 * 4);
        ak += a.x * wk.x + a.y * wk.y + a.z * wk.z + a.w * wk.w;
        av += a.x * wv.x + a.y * wv.y + a.z * wv.z + a.w * wv.w;
    }
    int h = t >> 5, dh = t & 31;
    out[h * 8192 + c * 32 + dh]         = ak;   // output 0: k
    out[65536 + h * 8192 + c * 32 + dh] = av;   // output 1: v
}

// ---------------------------------------------------------------------------
extern "C" void kernel_launch(void* const* d_in, const int* in_sizes, int n_in,
                              void* d_out, int out_size, void* d_ws, size_t ws_size,
                              hipStream_t stream) {
    (void)in_sizes; (void)n_in; (void)out_size; (void)ws_size;
    const float* x  = (const float*)d_in[0];  // [16,4096,256] f32
    const float* xm = (const float*)d_in[1];  // [256,256] f32
    const float* Wk = (const float*)d_in[2];  // [256,256] f32
    const float* Wv = (const float*)d_in[3];  // [256,256] f32

    float* ws       = (float*)d_ws;
    float* means_n  = ws;                     // 65536 f32
    float* inv_norm = ws + 65536;             // 65536 f32
    int*   buckets  = (int*)(ws + 131072);    // 65536 int
    float* sums     = ws + 196608;            // 65536 f32
    int*   bins     = (int*)(ws + 262144);    // 256 int
    unsigned short* mpk = (unsigned short*)(ws + 262400);  // 131072 bf16 (256KB)
    float* out      = (float*)d_out;

    k_prep   <<<256,  256, 0, stream>>>(xm, means_n, mpk, sums, bins);
    k_assign <<<1024, 256, 0, stream>>>(x, mpk, buckets, inv_norm, bins);
    k_scatter<<<dim3(64, 8), 256, 0, stream>>>(x, buckets, inv_norm, sums);
    k_xgkv   <<<256,  256, 0, stream>>>(sums, bins, means_n, Wk, Wv, out);
}

// Round 8
// 284.727 us; speedup vs baseline: 2.6043x; 1.0308x over previous
//
#include <hip/hip_runtime.h>
#include <hip/hip_bf16.h>
#include <stdint.h>

// Problem constants (b=16, l=4096, d=256, c=256, qk_dim=256, heads=8)
// Inputs: float32. Outputs: FLOAT32:
//   out[0..65536)       k  [8,256,32]
//   out[65536..131072)  v  [8,256,32]
//   out[131072..196608) x_global [256,256]
#define DD 256
#define CC 256

typedef __attribute__((ext_vector_type(8))) short bf16x8;
typedef __attribute__((ext_vector_type(4))) float f32x4;

// round-to-nearest-even f32 -> bf16; also returns the rounded value as f32
__device__ __forceinline__ unsigned short bf16_rn(float v, float& hval) {
    unsigned u = __builtin_bit_cast(unsigned, v);
    unsigned r = u + 0x7FFFu + ((u >> 16) & 1u);
    hval = __builtin_bit_cast(float, r & 0xFFFF0000u);
    return (unsigned short)(r >> 16);
}

// ---------------------------------------------------------------------------
// K1: normalize cluster means (f32); emit packed split-bf16 slices:
// mpk[kc(8)][ hi: [q(4)][c(256)][8] | lo: same ] (32KB per kc slice,
// contiguous for global_load_lds). Zero sums + bins.
__global__ __launch_bounds__(256) void k_prep(const float* __restrict__ xm,
                                              float* __restrict__ means_n,
                                              unsigned short* __restrict__ mpk,
                                              float* __restrict__ sums,
                                              int* __restrict__ bins) {
    __shared__ float red[256];
    int c = blockIdx.x, t = threadIdx.x;
    float v = xm[c * DD + t];
    red[t] = v * v;
    __syncthreads();
    for (int off = 128; off > 0; off >>= 1) {
        if (t < off) red[t] += red[t + off];
        __syncthreads();
    }
    float inv = 1.0f / fmaxf(sqrtf(red[0]), 1e-12f);
    float vn = v * inv;
    means_n[c * DD + t] = vn;
    float hf; unsigned short hb = bf16_rn(vn, hf);
    float lo = vn - hf;                 // exact
    float d2; unsigned short lb = bf16_rn(lo, d2);
    int kc = t >> 5, q = (t >> 3) & 3, j = t & 7;
    mpk[kc * 16384 + q * 2048 + c * 8 + j]        = hb;
    mpk[kc * 16384 + 8192 + q * 2048 + c * 8 + j] = lb;
    sums[c * DD + t] = 0.0f;
    if (c == 0) bins[t] = 0;
}

// ---------------------------------------------------------------------------
// K2 v4: MFMA similarity + argmax + inv-norm + bins.
// R7 lesson: single-buffer exposed the full global_load_lds latency between
// two barriers every kc (MfmaUtil 10%). v4: double-buffered 2x32KB with ONE
// barrier per kc: barrier(stage kc landed) -> issue stage(kc+1) into other
// buffer -> compute(kc). Stage latency hides under 48 MFMAs + convert.
// Buffer reuse safe: stage(kc+2) issues after the barrier proving all waves
// finished compute(kc). LDS 64KB -> 2 blocks/CU; launch_bounds(256,2) keeps
// the register allocator free (~120 unified regs incl 64 AGPR).
// 3-MFMA split-bf16 (hh+lh+hl): buckets bit-identical to f32 ref (R4-R7).
// C/D layout: cluster=ct*16+(lane&15), point=p0+q*4+reg.
__global__ __launch_bounds__(256, 2) void k_assign(
        const float* __restrict__ x,
        const unsigned short* __restrict__ mpk,
        int* __restrict__ buckets,
        float* __restrict__ inv_norm,
        int* __restrict__ bins) {
    __shared__ __align__(16) unsigned short mlds[2][16384];   // 2 x 32KB
    int t = threadIdx.x;
    int w = t >> 6, lane = t & 63;
    int m = lane & 15, q = lane >> 4;          // q in 0..3
    int p0 = blockIdx.x * 64 + w * 16;
    const float* xq = x + (size_t)(p0 + m) * DD + q * 8;

    f32x4 acc[16];
#pragma unroll
    for (int ct = 0; ct < 16; ct++) acc[ct] = (f32x4){0.f, 0.f, 0.f, 0.f};
    float ss = 0.f;

    // stage kc slice into buffer BUF: 32KB/block, 8KB/wave = 8 x (64 x 16B)
#define STAGE(KC, BUF) do {                                                     \
        const unsigned short* gsrc = mpk + (KC) * 16384 + w * 4096 + lane * 8;  \
        unsigned short* lb = &mlds[BUF][w * 4096];                              \
        _Pragma("unroll")                                                       \
        for (int i = 0; i < 8; i++)                                             \
            __builtin_amdgcn_global_load_lds(                                   \
                (const __attribute__((address_space(1))) void*)(gsrc + i * 512),\
                (__attribute__((address_space(3))) void*)(lb + i * 512),        \
                16, 0, 0);                                                      \
    } while (0)

    STAGE(0, 0);
    float4 nxa = *(const float4*)(xq);
    float4 nxb = *(const float4*)(xq + 4);

    for (int kc = 0; kc < 8; kc++) {
        __syncthreads();   // stage(kc) landed; all waves done with buf kc&1^1

        if (kc < 7) STAGE(kc + 1, (kc + 1) & 1);   // prefetch under compute

        float4 xa = nxa, xb = nxb;
        ss += xa.x * xa.x + xa.y * xa.y + xa.z * xa.z + xa.w * xa.w +
              xb.x * xb.x + xb.y * xb.y + xb.z * xb.z + xb.w * xb.w;
        float xv[8] = {xa.x, xa.y, xa.z, xa.w, xb.x, xb.y, xb.z, xb.w};
        bf16x8 ah, al;
#pragma unroll
        for (int j = 0; j < 8; j++) {
            float hf; unsigned short hb = bf16_rn(xv[j], hf);
            float lo = xv[j] - hf; float d2;
            al[j] = (short)bf16_rn(lo, d2); ah[j] = (short)hb;
        }
        if (kc < 7) {   // x prefetch: lands long before next barrier
            nxa = *(const float4*)(xq + (kc + 1) * 32);
            nxb = *(const float4*)(xq + (kc + 1) * 32 + 4);
        }

        const unsigned short* fb = &mlds[kc & 1][q * 2048 + m * 8];
#pragma unroll
        for (int ct = 0; ct < 16; ct++) {
            bf16x8 bh = *(const bf16x8*)(fb + ct * 128);
            bf16x8 bl = *(const bf16x8*)(fb + 8192 + ct * 128);
            acc[ct] = __builtin_amdgcn_mfma_f32_16x16x32_bf16(ah, bh, acc[ct], 0, 0, 0);
            acc[ct] = __builtin_amdgcn_mfma_f32_16x16x32_bf16(al, bh, acc[ct], 0, 0, 0);
            acc[ct] = __builtin_amdgcn_mfma_f32_16x16x32_bf16(ah, bl, acc[ct], 0, 0, 0);
        }
    }
#undef STAGE

    // row inv-norm: sum over the 4 q-lane groups (lane bits 4,5)
    ss += __shfl_xor(ss, 16, 64);
    ss += __shfl_xor(ss, 32, 64);
    if (q == 0) inv_norm[p0 + m] = 1.0f / fmaxf(sqrtf(ss), 1e-12f);

    // argmax: per-lane over ascending ct (strict > keeps lowest cluster)
    float bv[4]; int bi[4];
#pragma unroll
    for (int r = 0; r < 4; r++) {
        bv[r] = acc[0][r]; bi[r] = m;
#pragma unroll
        for (int ct = 1; ct < 16; ct++) {
            float v2 = acc[ct][r];
            if (v2 > bv[r]) { bv[r] = v2; bi[r] = ct * 16 + m; }
        }
    }
    // reduce across the 16 m-lanes; tie -> lowest cluster index
#pragma unroll
    for (int mask = 1; mask < 16; mask <<= 1) {
#pragma unroll
        for (int r = 0; r < 4; r++) {
            float ov = __shfl_xor(bv[r], mask, 64);
            int   oi = __shfl_xor(bi[r], mask, 64);
            if (ov > bv[r] || (ov == bv[r] && oi < bi[r])) { bv[r] = ov; bi[r] = oi; }
        }
    }
    if (m == 0) {
#pragma unroll
        for (int r = 0; r < 4; r++) {
            buckets[p0 + q * 4 + r] = bi[r];
            atomicAdd(&bins[bi[r]], 1);
        }
    }
}

// ---------------------------------------------------------------------------
// K3: scatter-add of normalized x into sums. LDS slab [256 clusters][32 coords]
// = 32KB. grid (64 point-chunks, 8 coord-chunks) = 512 blocks (2/CU).
__global__ __launch_bounds__(256) void k_scatter(const float* __restrict__ x,
                                                 const int* __restrict__ buckets,
                                                 const float* __restrict__ inv_norm,
                                                 float* __restrict__ sums) {
    __shared__ float acc[256 * 32];   // 32KB
    int t = threadIdx.x;
    for (int i = t; i < 256 * 32; i += 256) acc[i] = 0.0f;
    __syncthreads();
    int co = t & 31, pg = t >> 5;               // 8 point-groups
    int c0 = blockIdx.y * 32;
    int n0 = blockIdx.x * 1024;
    for (int i = 0; i < 128; i++) {
        int n = n0 + i * 8 + pg;
        int b = buckets[n] & 255;
        float wgt = inv_norm[n];
        float v = x[(size_t)n * DD + c0 + co] * wgt;
        atomicAdd(&acc[b * 32 + co], v);
    }
    __syncthreads();
    for (int k = 0; k < 32; k++) {
        int flat = k * 256 + t;
        atomicAdd(&sums[(flat >> 5) * DD + c0 + (flat & 31)], acc[flat]);
    }
}

// ---------------------------------------------------------------------------
// K4+K5 fused: x_global = l2norm(sums) (or old mean if empty bin), then
// k = xg @ Wk^T, v = xg @ Wv^T in [h][c][dh] layout. All f32. 256 blocks.
__global__ __launch_bounds__(256) void k_xgkv(const float* __restrict__ sums,
                                              const int* __restrict__ bins,
                                              const float* __restrict__ means_n,
                                              const float* __restrict__ Wk,
                                              const float* __restrict__ Wv,
                                              float* __restrict__ out) {
    __shared__ float red[256];
    __shared__ __align__(16) float xr[256];
    int c = blockIdx.x, t = threadIdx.x;
    float s = sums[c * DD + t];
    red[t] = s * s;
    __syncthreads();
    for (int off = 128; off > 0; off >>= 1) {
        if (t < off) red[t] += red[t + off];
        __syncthreads();
    }
    float g;
    if (bins[c] > 0) g = s / fmaxf(sqrtf(red[0]), 1e-12f);
    else             g = means_n[c * DD + t];
    out[131072 + c * DD + t] = g;   // output 2: x_global
    xr[t] = g;
    __syncthreads();

    float ak = 0.f, av = 0.f;
    const float4* wkp = (const float4*)(Wk + (size_t)t * DD);
    const float4* wvp = (const float4*)(Wv + (size_t)t * DD);
#pragma unroll 8
    for (int j4 = 0; j4 < 64; j4++) {
        float4 wk = wkp[j4], wv = wvp[j4];
        float4 a = *(const float4*)(xr + j4 * 4);
        ak += a.x * wk.x + a.y * wk.y + a.z * wk.z + a.w * wk.w;
        av += a.x * wv.x + a.y * wv.y + a.z * wv.z + a.w * wv.w;
    }
    int h = t >> 5, dh = t & 31;
    out[h * 8192 + c * 32 + dh]         = ak;   // output 0: k
    out[65536 + h * 8192 + c * 32 + dh] = av;   // output 1: v
}

// ---------------------------------------------------------------------------
extern "C" void kernel_launch(void* const* d_in, const int* in_sizes, int n_in,
                              void* d_out, int out_size, void* d_ws, size_t ws_size,
                              hipStream_t stream) {
    (void)in_sizes; (void)n_in; (void)out_size; (void)ws_size;
    const float* x  = (const float*)d_in[0];  // [16,4096,256] f32
    const float* xm = (const float*)d_in[1];  // [256,256] f32
    const float* Wk = (const float*)d_in[2];  // [256,256] f32
    const float* Wv = (const float*)d_in[3];  // [256,256] f32

    float* ws       = (float*)d_ws;
    float* means_n  = ws;                     // 65536 f32
    float* inv_norm = ws + 65536;             // 65536 f32
    int*   buckets  = (int*)(ws + 131072);    // 65536 int
    float* sums     = ws + 196608;            // 65536 f32
    int*   bins     = (int*)(ws + 262144);    // 256 int
    unsigned short* mpk = (unsigned short*)(ws + 262400);  // 131072 bf16 (256KB)
    float* out      = (float*)d_out;

    k_prep   <<<256,  256, 0, stream>>>(xm, means_n, mpk, sums, bins);
    k_assign <<<1024, 256, 0, stream>>>(x, mpk, buckets, inv_norm, bins);
    k_scatter<<<dim3(64, 8), 256, 0, stream>>>(x, buckets, inv_norm, sums);
    k_xgkv   <<<256,  256, 0, stream>>>(sums, bins, means_n, Wk, Wv, out);
}